// Round 11
// baseline (424.845 us; speedup 1.0000x reference)
//
#include <hip/hip_runtime.h>

#define HW 65536
#define W_IMG 256
#define H_IMG 256
#define CIN 64
#define CHID 384
#define CQK 128

// ---------------- K1: 1x1 expansion GEMM (LDS-free, ping-pong, split stores) ----------------
// block = 48co x 256px, 4 waves; TWO sequential 6-co groups per wave so group-0
// stores (48 MB) drain under group-1 compute instead of in an end-of-kernel burst.
__global__ __launch_bounds__(256) void k1_expand(
    const float* __restrict__ x_base,    // [B][CIN][HW]
    const float* __restrict__ wh,        // [CHID][CIN]
    const float* __restrict__ bh,        // [CHID]
    float* __restrict__ hidden_base,     // [B][CHID][HW]
    size_t x_bstride, size_t hid_bstride)
{
    const float* x = x_base + blockIdx.z * x_bstride;
    float* hidden  = hidden_base + blockIdx.z * hid_bstride;
    const int pxbase = blockIdx.x * 256;
    const int cobase = blockIdx.y * 48;
    const int tid  = threadIdx.x;
    const int lane = tid & 63;
    const int wq   = __builtin_amdgcn_readfirstlane(tid >> 6);
    const int px   = pxbase + lane * 4;

    #pragma unroll
    for (int g = 0; g < 2; ++g) {
        const int cw = cobase + g * 24 + wq * 6;   // wave-uniform
        float acc[6][4];
        #pragma unroll
        for (int i = 0; i < 6; ++i)
            #pragma unroll
            for (int j = 0; j < 4; ++j) acc[i][j] = 0.f;

        float4 xa[4], xb[4];
        #pragma unroll
        for (int u = 0; u < 4; ++u)
            xa[u] = *reinterpret_cast<const float4*>(&x[(size_t)u * HW + px]);

        #pragma unroll 1
        for (int ci4 = 0; ci4 < CIN; ci4 += 8) {
            #pragma unroll
            for (int u = 0; u < 4; ++u)
                xb[u] = *reinterpret_cast<const float4*>(&x[(size_t)(ci4 + 4 + u) * HW + px]);
            #pragma unroll
            for (int i = 0; i < 6; ++i) {
                float4 wv = *reinterpret_cast<const float4*>(
                    &wh[(size_t)(cw + i) * CIN + ci4]);        // wave-uniform -> s_load
                float wu[4] = {wv.x, wv.y, wv.z, wv.w};
                #pragma unroll
                for (int u = 0; u < 4; ++u) {
                    acc[i][0] += wu[u] * xa[u].x;
                    acc[i][1] += wu[u] * xa[u].y;
                    acc[i][2] += wu[u] * xa[u].z;
                    acc[i][3] += wu[u] * xa[u].w;
                }
            }
            if (ci4 + 8 < CIN) {
                #pragma unroll
                for (int u = 0; u < 4; ++u)
                    xa[u] = *reinterpret_cast<const float4*>(&x[(size_t)(ci4 + 8 + u) * HW + px]);
            }
            #pragma unroll
            for (int i = 0; i < 6; ++i) {
                float4 wv = *reinterpret_cast<const float4*>(
                    &wh[(size_t)(cw + i) * CIN + ci4 + 4]);
                float wu[4] = {wv.x, wv.y, wv.z, wv.w};
                #pragma unroll
                for (int u = 0; u < 4; ++u) {
                    acc[i][0] += wu[u] * xb[u].x;
                    acc[i][1] += wu[u] * xb[u].y;
                    acc[i][2] += wu[u] * xb[u].z;
                    acc[i][3] += wu[u] * xb[u].w;
                }
            }
        }

        #pragma unroll
        for (int i = 0; i < 6; ++i) {
            int co = cw + i;
            float b = bh[co];
            float4 o;
            o.x = acc[i][0] + b; o.y = acc[i][1] + b;
            o.z = acc[i][2] + b; o.w = acc[i][3] + b;
            *reinterpret_cast<float4*>(&hidden[(size_t)co * HW + px]) = o;
        }
    }
}

// ---------------- K2: fused depthwise 3x3 + 8x8 circular conv + v-mul ----------------
// v8: depthwise q,k straight from global; w+-1 halo via __shfl (row == 32 lanes,
// lane boundaries == image edges). LDS = qk only (17.7 KB); ONE barrier total.
#define QK_CH   2208   // 8*276 floats
#define QK_ROW  276
#define QK_SEG  68
__global__ __launch_bounds__(256) void k2_fused(
    const float* __restrict__ hidden_base,  // [B][CHID][HW]
    const float* __restrict__ wdw,          // [CHID][9]
    const float* __restrict__ bdw,          // [CHID]
    float* __restrict__ vout_base,          // [B][CQK][HW]
    size_t hid_bstride, size_t vout_bstride)
{
    __shared__ float qk[2 * QK_CH];      // depthwise q,k results only

    const float* hidden = hidden_base + blockIdx.z * hid_bstride;
    float* vout         = vout_base + blockIdx.z * vout_bstride;

    const int c  = blockIdx.y;
    const int r0 = blockIdx.x * 8;
    const int tid = threadIdx.x;

    // dw-phase mapping: thread = (row, 8-px slice)
    const int row   = tid >> 5;          // 0..7
    const int col32 = tid & 31;          // slice id within row
    const int px8   = col32 * 8;         // first owned px
    const int gro   = r0 + row;

    // ---- issue q,k row loads up front (all in flight together)
    float4 qa0[3], qa1[3], ka0[3], ka1[3];
    #pragma unroll
    for (int ky = 0; ky < 3; ++ky) {
        int grr = gro + ky - 1;
        qa0[ky] = make_float4(0.f,0.f,0.f,0.f); qa1[ky] = qa0[ky];
        ka0[ky] = qa0[ky];                      ka1[ky] = qa0[ky];
        if ((unsigned)grr < H_IMG) {
            const float* rq = hidden + (size_t)c * HW + (size_t)grr * W_IMG;
            const float* rk = hidden + (size_t)(c + CQK) * HW + (size_t)grr * W_IMG;
            qa0[ky] = *reinterpret_cast<const float4*>(&rq[px8]);
            qa1[ky] = *reinterpret_cast<const float4*>(&rq[px8 + 4]);
            ka0[ky] = *reinterpret_cast<const float4*>(&rk[px8]);
            ka1[ky] = *reinterpret_cast<const float4*>(&rk[px8 + 4]);
        }
    }

    // ---- depthwise q then k, edges via shfl
    #pragma unroll
    for (int ch = 0; ch < 2; ++ch) {
        const float4* a0 = ch ? ka0 : qa0;
        const float4* a1 = ch ? ka1 : qa1;
        const float* wv = wdw + (c + ch * CQK) * 9;   // block-uniform -> scalar
        const float bias = bdw[c + ch * CQK];

        float accd[8];
        #pragma unroll
        for (int j = 0; j < 8; ++j) accd[j] = bias;

        #pragma unroll
        for (int ky = 0; ky < 3; ++ky) {
            float kw0 = wv[ky * 3], kw1 = wv[ky * 3 + 1], kw2 = wv[ky * 3 + 2];
            float lf = __shfl_up(a1[ky].w, 1);    // prev slice's px8+7
            float rt = __shfl_down(a0[ky].x, 1);  // next slice's px8
            if (col32 == 0)  lf = 0.f;            // px -1 (also fixes row-crossing)
            if (col32 == 31) rt = 0.f;            // px 256
            float h[10] = {lf, a0[ky].x, a0[ky].y, a0[ky].z, a0[ky].w,
                               a1[ky].x, a1[ky].y, a1[ky].z, a1[ky].w, rt};
            #pragma unroll
            for (int j = 0; j < 8; ++j)
                accd[j] += h[j] * kw0 + h[j + 1] * kw1 + h[j + 2] * kw2;
        }

        float* dst = &qk[ch * QK_CH + row * QK_ROW + (px8 >> 6) * QK_SEG + (px8 & 63)];
        float4 o0, o1;
        o0.x = accd[0]; o0.y = accd[1]; o0.z = accd[2]; o0.w = accd[3];
        o1.x = accd[4]; o1.y = accd[5]; o1.z = accd[6]; o1.w = accd[7];
        *reinterpret_cast<float4*>(dst)     = o0;
        *reinterpret_cast<float4*>(dst + 4) = o1;
    }

    // ---- phase-2 mapping + v loads (consumed after the 512-FMA conv: latency hidden)
    const int seg = (tid >> 3) & 3;
    const int i   = tid & 7;
    const int gr  = r0 + row;            // same row id
    const int wp0 = seg * 64 + i * 8;

    const float* hbv = hidden + (size_t)(c + 2 * CQK) * HW;
    float4 hv[3][2];
    float  hm[3], hp[3];
    #pragma unroll
    for (int ky = 0; ky < 3; ++ky) {
        int grr = gr + ky - 1;
        hv[ky][0] = make_float4(0.f,0.f,0.f,0.f);
        hv[ky][1] = make_float4(0.f,0.f,0.f,0.f);
        hm[ky] = 0.f; hp[ky] = 0.f;
        if ((unsigned)grr < H_IMG) {
            const float* rb = hbv + (size_t)grr * W_IMG;
            hv[ky][0] = *reinterpret_cast<const float4*>(&rb[wp0]);
            hv[ky][1] = *reinterpret_cast<const float4*>(&rb[wp0 + 4]);
            hm[ky] = (wp0 > 0)   ? rb[wp0 - 1] : 0.f;
            hp[ky] = (wp0 < 248) ? rb[wp0 + 8] : 0.f;
        }
    }

    __syncthreads();                     // the ONLY barrier

    // ---- phase 2: 8x8 circular conv + v depthwise (regs) + multiply
    const float* qb = &qk[row * QK_ROW + seg * QK_SEG];
    const float* kb = &qk[QK_CH + row * QK_ROW + seg * QK_SEG];

    float acc[8];
    #pragma unroll
    for (int j = 0; j < 8; ++j) acc[j] = 0.f;

    #pragma unroll
    for (int s = 0; s < 8; ++s) {
        int qr = (i - s) & 7;
        float4 ka = *reinterpret_cast<const float4*>(&kb[s * 8]);
        float4 kc = *reinterpret_cast<const float4*>(&kb[s * 8 + 4]);
        float4 qa = *reinterpret_cast<const float4*>(&qb[qr * 8]);
        float4 qc = *reinterpret_cast<const float4*>(&qb[qr * 8 + 4]);
        float kr[8] = {ka.x, ka.y, ka.z, ka.w, kc.x, kc.y, kc.z, kc.w};
        float qv[8] = {qa.x, qa.y, qa.z, qa.w, qc.x, qc.y, qc.z, qc.w};
        #pragma unroll
        for (int t = 0; t < 8; ++t)
            #pragma unroll
            for (int j = 0; j < 8; ++j)
                acc[j] += kr[t] * qv[(j - t) & 7];
    }

    const float* wvv = wdw + (c + 2 * CQK) * 9;
    const float vbias = bdw[c + 2 * CQK];
    float vc[8];
    #pragma unroll
    for (int j = 0; j < 8; ++j) vc[j] = vbias;
    #pragma unroll
    for (int ky = 0; ky < 3; ++ky) {
        float kw0 = wvv[ky * 3], kw1 = wvv[ky * 3 + 1], kw2 = wvv[ky * 3 + 2];
        float h[10];
        h[0] = hm[ky];
        h[1] = hv[ky][0].x; h[2] = hv[ky][0].y; h[3] = hv[ky][0].z; h[4] = hv[ky][0].w;
        h[5] = hv[ky][1].x; h[6] = hv[ky][1].y; h[7] = hv[ky][1].z; h[8] = hv[ky][1].w;
        h[9] = hp[ky];
        #pragma unroll
        for (int j = 0; j < 8; ++j)
            vc[j] += h[j] * kw0 + h[j + 1] * kw1 + h[j + 2] * kw2;
    }

    float* dst = &vout[(size_t)c * HW + (size_t)gr * W_IMG + wp0];
    float4 o0, o1;
    o0.x = acc[0] * vc[0]; o0.y = acc[1] * vc[1];
    o0.z = acc[2] * vc[2]; o0.w = acc[3] * vc[3];
    o1.x = acc[4] * vc[4]; o1.y = acc[5] * vc[5];
    o1.z = acc[6] * vc[6]; o1.w = acc[7] * vc[7];
    *reinterpret_cast<float4*>(dst)     = o0;
    *reinterpret_cast<float4*>(dst + 4) = o1;
}

// ---------------- K3: 1x1 projection GEMM (LDS-free, ping-pong prefetch) ----------------
__global__ __launch_bounds__(256) void k3_project(
    const float* __restrict__ vout_base,  // [B][CQK][HW]
    const float* __restrict__ wo,         // [64][CQK]
    const float* __restrict__ bo,         // [64]
    float* __restrict__ out_base,         // [B][64][HW]
    size_t vout_bstride, size_t out_bstride)
{
    const float* vout = vout_base + blockIdx.z * vout_bstride;
    float* out        = out_base + blockIdx.z * out_bstride;
    const int pxbase = blockIdx.x * 256;
    const int cobase = blockIdx.y * 16;
    const int tid  = threadIdx.x;
    const int lane = tid & 63;
    const int wq   = __builtin_amdgcn_readfirstlane(tid >> 6);
    const int px   = pxbase + lane * 4;
    const int cw   = cobase + wq * 4;     // wave-uniform

    float acc[4][4];
    #pragma unroll
    for (int i = 0; i < 4; ++i)
        #pragma unroll
        for (int j = 0; j < 4; ++j) acc[i][j] = 0.f;

    float4 xa[4], xb[4];
    #pragma unroll
    for (int u = 0; u < 4; ++u)
        xa[u] = *reinterpret_cast<const float4*>(&vout[(size_t)u * HW + px]);

    #pragma unroll 1
    for (int cc4 = 0; cc4 < CQK; cc4 += 8) {
        #pragma unroll
        for (int u = 0; u < 4; ++u)
            xb[u] = *reinterpret_cast<const float4*>(&vout[(size_t)(cc4 + 4 + u) * HW + px]);
        #pragma unroll
        for (int i = 0; i < 4; ++i) {
            float4 wv = *reinterpret_cast<const float4*>(
                &wo[(size_t)(cw + i) * CQK + cc4]);   // uniform -> s_load
            float wu[4] = {wv.x, wv.y, wv.z, wv.w};
            #pragma unroll
            for (int u = 0; u < 4; ++u) {
                acc[i][0] += wu[u] * xa[u].x;
                acc[i][1] += wu[u] * xa[u].y;
                acc[i][2] += wu[u] * xa[u].z;
                acc[i][3] += wu[u] * xa[u].w;
            }
        }
        if (cc4 + 8 < CQK) {
            #pragma unroll
            for (int u = 0; u < 4; ++u)
                xa[u] = *reinterpret_cast<const float4*>(&vout[(size_t)(cc4 + 8 + u) * HW + px]);
        }
        #pragma unroll
        for (int i = 0; i < 4; ++i) {
            float4 wv = *reinterpret_cast<const float4*>(
                &wo[(size_t)(cw + i) * CQK + cc4 + 4]);
            float wu[4] = {wv.x, wv.y, wv.z, wv.w};
            #pragma unroll
            for (int u = 0; u < 4; ++u) {
                acc[i][0] += wu[u] * xb[u].x;
                acc[i][1] += wu[u] * xb[u].y;
                acc[i][2] += wu[u] * xb[u].z;
                acc[i][3] += wu[u] * xb[u].w;
            }
        }
    }

    #pragma unroll
    for (int i = 0; i < 4; ++i) {
        int co = cw + i;
        float b = bo[co];
        float4 o;
        o.x = acc[i][0] + b; o.y = acc[i][1] + b;
        o.z = acc[i][2] + b; o.w = acc[i][3] + b;
        *reinterpret_cast<float4*>(&out[(size_t)co * HW + px]) = o;
    }
}

extern "C" void kernel_launch(void* const* d_in, const int* in_sizes, int n_in,
                              void* d_out, int out_size, void* d_ws, size_t ws_size,
                              hipStream_t stream) {
    const float* x   = (const float*)d_in[0];
    const float* wh  = (const float*)d_in[1];
    const float* bh  = (const float*)d_in[2];
    const float* wdw = (const float*)d_in[3];
    const float* bdw = (const float*)d_in[4];
    const float* wo  = (const float*)d_in[5];
    const float* bo  = (const float*)d_in[6];
    float* out = (float*)d_out;

    const size_t n_hid  = (size_t)CHID * HW;
    const size_t n_vout = (size_t)CQK * HW;
    const size_t n_x    = (size_t)CIN * HW;

    if (ws_size >= 4 * (n_hid + n_vout) * sizeof(float)) {
        float* hidden = (float*)d_ws;
        float* vout   = hidden + 4 * n_hid;
        k1_expand <<<dim3(HW / 256, CHID / 48, 4), 256, 0, stream>>>(
            x, wh, bh, hidden, n_x, n_hid);
        k2_fused  <<<dim3(H_IMG / 8, CQK, 4),      256, 0, stream>>>(
            hidden, wdw, bdw, vout, n_hid, n_vout);
        k3_project<<<dim3(HW / 256, 64 / 16, 4),   256, 0, stream>>>(
            vout, wo, bo, out, n_vout, n_x);
    } else {
        float* hidden = (float*)d_ws;
        float* vout   = hidden + n_hid;
        for (int b = 0; b < 4; ++b) {
            const float* xb = x + (size_t)b * n_x;
            float* ob       = out + (size_t)b * n_x;
            k1_expand <<<dim3(HW / 256, CHID / 48, 1), 256, 0, stream>>>(
                xb, wh, bh, hidden, 0, 0);
            k2_fused  <<<dim3(H_IMG / 8, CQK, 1),      256, 0, stream>>>(
                hidden, wdw, bdw, vout, 0, 0);
            k3_project<<<dim3(HW / 256, 64 / 16, 1),   256, 0, stream>>>(
                vout, wo, bo, ob, 0, 0);
        }
    }
}